// Round 1
// baseline (711.162 us; speedup 1.0000x reference)
//
#include <hip/hip_runtime.h>
#include <hip/hip_bf16.h>
#include <cstdint>
#include <cstddef>

#define B_   2
#define C_   512
#define N_   4096
#define NH   4
#define DH_  32
#define HID  128
#define LOG2E 1.4426950408889634f

typedef __attribute__((ext_vector_type(8))) short bf16x8;
typedef __attribute__((ext_vector_type(4))) float f32x4;

#if __has_builtin(__builtin_amdgcn_exp2f)
#define EXP2(x) __builtin_amdgcn_exp2f(x)
#else
#define EXP2(x) exp2f(x)
#endif

static __device__ __forceinline__ unsigned short f2bf(float f) {
  union { float f; unsigned int u; } v; v.f = f;
  unsigned int r = v.u + 0x7fffu + ((v.u >> 16) & 1u);
  return (unsigned short)(r >> 16);
}

// ---------------------------------------------------------------------------
// Kernel 1: QKV 1x1-conv projections.
//   q,k -> bf16 [b][h][n][32] (row-major d)   v -> bf16 [b][h][32][n] (transposed)
// grid = 3 tensors * B * 64 n-tiles = 384 blocks, 256 threads
// ---------------------------------------------------------------------------
__global__ __launch_bounds__(256)
void qkv_proj(const float* __restrict__ x,
              const float* __restrict__ wq, const float* __restrict__ bq,
              const float* __restrict__ wk, const float* __restrict__ bk,
              const float* __restrict__ wv, const float* __restrict__ bv,
              unsigned short* __restrict__ qws,
              unsigned short* __restrict__ kws,
              unsigned short* __restrict__ vtws)
{
  int bid = blockIdx.x;
  int tensor = bid >> 7;           // 0=q 1=k 2=v
  int rem = bid & 127;
  int b  = rem >> 6;
  int n0 = (rem & 63) << 6;        // 64-wide n tile
  const float* w; const float* bs;
  if (tensor == 0)      { w = wq; bs = bq; }
  else if (tensor == 1) { w = wk; bs = bk; }
  else                  { w = wv; bs = bv; }

  int tid = threadIdx.x;
  int nn = tid & 63;               // n within tile (lane)
  int og = tid >> 6;               // head group 0..3  (wave-uniform)

  __shared__ float xs[16][64];

  float acc[32];
#pragma unroll
  for (int j = 0; j < 32; j++) acc[j] = bs[og * 32 + j];

  const float* xb = x + (size_t)b * C_ * N_ + n0;

  for (int c0 = 0; c0 < C_; c0 += 16) {
    __syncthreads();
#pragma unroll
    for (int rr = 0; rr < 4; rr++) {
      int cc = rr * 4 + og;
      xs[cc][nn] = xb[(size_t)(c0 + cc) * N_ + nn];
    }
    __syncthreads();

    float xv[16];
#pragma unroll
    for (int cc = 0; cc < 16; cc++) xv[cc] = xs[cc][nn];

    const float* wbase = w + (size_t)(og * 32) * C_ + c0;
#pragma unroll
    for (int j = 0; j < 32; j++) {
      const float* wr = wbase + (size_t)j * C_;
#pragma unroll
      for (int q4 = 0; q4 < 4; q4++) {
        float4 wv = *(const float4*)(wr + q4 * 4);
        acc[j] = fmaf(wv.x, xv[q4 * 4 + 0], acc[j]);
        acc[j] = fmaf(wv.y, xv[q4 * 4 + 1], acc[j]);
        acc[j] = fmaf(wv.z, xv[q4 * 4 + 2], acc[j]);
        acc[j] = fmaf(wv.w, xv[q4 * 4 + 3], acc[j]);
      }
    }
  }

  int n = n0 + nn;
  if (tensor < 2) {
    unsigned short* dst = (tensor == 0 ? qws : kws)
                        + (((size_t)(b * NH + og)) * N_ + n) * DH_;
    alignas(16) unsigned short tmp[32];
#pragma unroll
    for (int j = 0; j < 32; j++) tmp[j] = f2bf(acc[j]);
#pragma unroll
    for (int t = 0; t < 4; t++) ((uint4*)dst)[t] = ((const uint4*)tmp)[t];
  } else {
    unsigned short* dst = vtws + ((size_t)(b * NH + og)) * DH_ * N_ + n;
#pragma unroll
    for (int j = 0; j < 32; j++) dst[(size_t)j * N_] = f2bf(acc[j]);
  }
}

// ---------------------------------------------------------------------------
// Kernel 2: fused scores -> head-fuse -> softmax -> p write -> PV
// grid = B * 256 q-tiles = 512 blocks, 256 threads (4 waves split m)
// ---------------------------------------------------------------------------
__global__ __launch_bounds__(256)
void attn_fused(const unsigned short* __restrict__ qws,
                const unsigned short* __restrict__ kws,
                const unsigned short* __restrict__ vtws,
                const float* __restrict__ wfuse,
                float* __restrict__ attn_out,    // d_out + B*C*N
                float* __restrict__ pre)         // ws, f32 [b][128][n]
{
  int bid = blockIdx.x;
  int b  = bid >> 8;
  int qt = bid & 255;
  int n0 = qt << 4;                 // 16 query rows per block

  int tid = threadIdx.x;
  int wv_ = tid >> 6;               // wave 0..3
  int l   = tid & 63;
  int lg  = l >> 4;                 // 0..3
  int lc  = l & 15;                 // 0..15

  __shared__ float zlds[4][4][16];
  __shared__ unsigned short pbuf[4][4][16][40];  // [wave][g][n][m(32)+pad]
  __shared__ float obuf[4][4][16][33];           // [wave][g][n][d(32)+pad]

  const float TEMP = 11.313708498984761f;        // sqrt(128)
  float wm[4][4];
#pragma unroll
  for (int g = 0; g < 4; g++)
#pragma unroll
    for (int h = 0; h < 4; h++)
      wm[g][h] = wfuse[g * 4 + h] * (LOG2E / TEMP);

  // Q fragments: A-frag elem j = Q[n0 + lc][lg*8 + j]
  bf16x8 qf[4];
#pragma unroll
  for (int h = 0; h < 4; h++)
    qf[h] = *(const bf16x8*)(qws + (((size_t)(b * NH + h)) * N_ + n0 + lc) * DH_ + lg * 8);

  const f32x4 zc = {0.f, 0.f, 0.f, 0.f};

  // ---------------- pass 1: Z = sum of 2^s ----------------
  float zp[4][4] = {};
  for (int pp = wv_; pp < 128; pp += 4) {
#pragma unroll
    for (int mm = 0; mm < 2; mm++) {
      int m0 = pp * 32 + mm * 16;
      f32x4 sh[4];
#pragma unroll
      for (int h = 0; h < 4; h++) {
        bf16x8 kf = *(const bf16x8*)(kws + (((size_t)(b * NH + h)) * N_ + m0 + lc) * DH_ + lg * 8);
        sh[h] = __builtin_amdgcn_mfma_f32_16x16x32_bf16(qf[h], kf, zc, 0, 0, 0);
      }
#pragma unroll
      for (int g = 0; g < 4; g++) {
        f32x4 sg = wm[g][0] * sh[0] + wm[g][1] * sh[1]
                 + wm[g][2] * sh[2] + wm[g][3] * sh[3];
#pragma unroll
        for (int r = 0; r < 4; r++) zp[g][r] += EXP2(sg[r]);
      }
    }
  }

  // reduce across the 16 cols (lanes within 16-lane group)
#pragma unroll
  for (int g = 0; g < 4; g++)
#pragma unroll
    for (int r = 0; r < 4; r++) {
      float v = zp[g][r];
      v += __shfl_xor(v, 1, 16);
      v += __shfl_xor(v, 2, 16);
      v += __shfl_xor(v, 4, 16);
      v += __shfl_xor(v, 8, 16);
      zp[g][r] = v;
    }
  if (lc == 0) {
#pragma unroll
    for (int g = 0; g < 4; g++)
#pragma unroll
      for (int r = 0; r < 4; r++) zlds[wv_][g][lg * 4 + r] = zp[g][r];
  }
  __syncthreads();

  float invZ[4][4];
#pragma unroll
  for (int g = 0; g < 4; g++)
#pragma unroll
    for (int r = 0; r < 4; r++) {
      int row = lg * 4 + r;
      invZ[g][r] = 1.0f / (zlds[0][g][row] + zlds[1][g][row]
                         + zlds[2][g][row] + zlds[3][g][row]);
    }

  // ---------------- pass 2: write p, accumulate PV ----------------
  f32x4 opv[4][2];
#pragma unroll
  for (int g = 0; g < 4; g++) { opv[g][0] = zc; opv[g][1] = zc; }

  float* attn_b = attn_out + (size_t)b * NH * N_ * N_;

  for (int pp = wv_; pp < 128; pp += 4) {
#pragma unroll
    for (int mm = 0; mm < 2; mm++) {
      int m0 = pp * 32 + mm * 16;
      f32x4 sh[4];
#pragma unroll
      for (int h = 0; h < 4; h++) {
        bf16x8 kf = *(const bf16x8*)(kws + (((size_t)(b * NH + h)) * N_ + m0 + lc) * DH_ + lg * 8);
        sh[h] = __builtin_amdgcn_mfma_f32_16x16x32_bf16(qf[h], kf, zc, 0, 0, 0);
      }
#pragma unroll
      for (int g = 0; g < 4; g++) {
        f32x4 sg = wm[g][0] * sh[0] + wm[g][1] * sh[1]
                 + wm[g][2] * sh[2] + wm[g][3] * sh[3];
#pragma unroll
        for (int r = 0; r < 4; r++) {
          int row = lg * 4 + r;
          float p = EXP2(sg[r]) * invZ[g][r];
          attn_b[((size_t)g * N_ + (n0 + row)) * N_ + m0 + lc] = p;
          pbuf[wv_][g][row][mm * 16 + lc] = f2bf(p);
        }
      }
    }
    // PV over this 32-m pair (per-wave private pbuf; wave-coherent LDS)
    int m0p = pp * 32;
#pragma unroll
    for (int g = 0; g < 4; g++) {
      bf16x8 pa = *(const bf16x8*)(&pbuf[wv_][g][lc][lg * 8]);
#pragma unroll
      for (int dh = 0; dh < 2; dh++) {
        bf16x8 vb = *(const bf16x8*)(vtws
            + (((size_t)(b * NH + g)) * DH_ + dh * 16 + lc) * N_ + m0p + lg * 8);
        opv[g][dh] = __builtin_amdgcn_mfma_f32_16x16x32_bf16(pa, vb, opv[g][dh], 0, 0, 0);
      }
    }
  }

  // stage per-wave PV partials, reduce across waves
#pragma unroll
  for (int g = 0; g < 4; g++)
#pragma unroll
    for (int dh = 0; dh < 2; dh++)
#pragma unroll
      for (int r = 0; r < 4; r++)
        obuf[wv_][g][lg * 4 + r][dh * 16 + lc] = opv[g][dh][r];
  __syncthreads();

  int o  = tid >> 1;          // 0..127
  int nb = (tid & 1) * 8;
  int g2 = o >> 5;
  int d2 = o & 31;
#pragma unroll
  for (int i = 0; i < 8; i++) {
    int n = nb + i;
    float v = obuf[0][g2][n][d2] + obuf[1][g2][n][d2]
            + obuf[2][g2][n][d2] + obuf[3][g2][n][d2];
    pre[((size_t)b * HID + o) * N_ + n0 + n] = v;
  }
}

// ---------------------------------------------------------------------------
// Kernel 3: out projection (128 -> 512) + BatchNorm (eval)
// grid = B * 64 n-tiles * 4 co-tiles = 512 blocks, 256 threads
// ---------------------------------------------------------------------------
__global__ __launch_bounds__(256)
void outproj_bn(const float* __restrict__ pre,
                const float* __restrict__ wout, const float* __restrict__ bout,
                const float* __restrict__ gamma, const float* __restrict__ beta,
                const float* __restrict__ mean,  const float* __restrict__ var,
                float* __restrict__ out)
{
  int bid = blockIdx.x;
  int cot = bid & 3;
  int rem = bid >> 2;
  int b   = rem >> 6;
  int n0  = (rem & 63) << 6;
  int co0 = cot << 7;

  int tid = threadIdx.x;
  int nn = tid & 63;
  int cg = tid >> 6;

  __shared__ float ps[16][64];
  float acc[32];
#pragma unroll
  for (int j = 0; j < 32; j++) acc[j] = bout[co0 + cg * 32 + j];

  const float* pb = pre + (size_t)b * HID * N_ + n0;

  for (int o0 = 0; o0 < HID; o0 += 16) {
    __syncthreads();
#pragma unroll
    for (int rr = 0; rr < 4; rr++) {
      int oo = rr * 4 + cg;
      ps[oo][nn] = pb[(size_t)(o0 + oo) * N_ + nn];
    }
    __syncthreads();

    float xv[16];
#pragma unroll
    for (int oo = 0; oo < 16; oo++) xv[oo] = ps[oo][nn];

    const float* wbase = wout + (size_t)(co0 + cg * 32) * HID + o0;
#pragma unroll
    for (int j = 0; j < 32; j++) {
      const float* wr = wbase + (size_t)j * HID;
#pragma unroll
      for (int q4 = 0; q4 < 4; q4++) {
        float4 wv = *(const float4*)(wr + q4 * 4);
        acc[j] = fmaf(wv.x, xv[q4 * 4 + 0], acc[j]);
        acc[j] = fmaf(wv.y, xv[q4 * 4 + 1], acc[j]);
        acc[j] = fmaf(wv.z, xv[q4 * 4 + 2], acc[j]);
        acc[j] = fmaf(wv.w, xv[q4 * 4 + 3], acc[j]);
      }
    }
  }

#pragma unroll
  for (int j = 0; j < 32; j++) {
    int co = co0 + cg * 32 + j;
    float sc = gamma[co] * rsqrtf(var[co] + 1e-5f);
    float v  = (acc[j] - mean[co]) * sc + beta[co];
    out[((size_t)b * C_ + co) * N_ + n0 + nn] = v;
  }
}

// ---------------------------------------------------------------------------
extern "C" void kernel_launch(void* const* d_in, const int* in_sizes, int n_in,
                              void* d_out, int out_size, void* d_ws, size_t ws_size,
                              hipStream_t stream)
{
  const float* x     = (const float*)d_in[0];
  const float* wq    = (const float*)d_in[1];
  const float* bq    = (const float*)d_in[2];
  const float* wk    = (const float*)d_in[3];
  const float* bk    = (const float*)d_in[4];
  const float* wv    = (const float*)d_in[5];
  const float* bv    = (const float*)d_in[6];
  const float* wfuse = (const float*)d_in[7];
  const float* wout  = (const float*)d_in[8];
  const float* bout  = (const float*)d_in[9];
  const float* gamma = (const float*)d_in[10];
  const float* beta  = (const float*)d_in[11];
  const float* mean  = (const float*)d_in[12];
  const float* var   = (const float*)d_in[13];

  // workspace layout (bytes):
  //   [0, 2M)   q  bf16 [2][4][4096][32]
  //   [2M, 4M)  k  bf16 [2][4][4096][32]
  //   [4M, 6M)  vT bf16 [2][4][32][4096]
  //   [6M,10M)  pre f32 [2][128][4096]
  const size_t QK_ELEMS = (size_t)B_ * NH * N_ * DH_;   // 1,048,576
  unsigned short* qws  = (unsigned short*)d_ws;
  unsigned short* kws  = qws + QK_ELEMS;
  unsigned short* vtws = kws + QK_ELEMS;
  float* pre = (float*)((char*)d_ws + 3 * QK_ELEMS * sizeof(unsigned short));

  float* out_f  = (float*)d_out;                         // [2][512][4096]
  float* attn_f = out_f + (size_t)B_ * C_ * N_;          // [2][4][4096][4096]

  hipLaunchKernelGGL(qkv_proj, dim3(384), dim3(256), 0, stream,
                     x, wq, bq, wk, bk, wv, bv, qws, kws, vtws);
  hipLaunchKernelGGL(attn_fused, dim3(512), dim3(256), 0, stream,
                     qws, kws, vtws, wfuse, attn_f, pre);
  hipLaunchKernelGGL(outproj_bn, dim3(512), dim3(256), 0, stream,
                     pre, wout, bout, gamma, beta, mean, var, out_f);
}